// Round 1
// baseline (191.253 us; speedup 1.0000x reference)
//
#include <hip/hip_runtime.h>
#include <hip/hip_bf16.h>

typedef __attribute__((ext_vector_type(8))) short bf16x8;
typedef __attribute__((ext_vector_type(4))) float f32x4;

#define MARGIN 0.3f

__device__ __forceinline__ void gl2lds16(const void* g, void* l) {
    __builtin_amdgcn_global_load_lds(
        (const __attribute__((address_space(1))) void*)g,
        (__attribute__((address_space(3))) void*)l,
        16, 0, 0);
}

// One block per row: fp32 -> bf16 cast, fp32 row norm (of the bf16-rounded
// values, for consistency with the MFMA dot products), and init ap/an.
__global__ __launch_bounds__(256) void convert_norm_kernel(
    const float* __restrict__ X, __hip_bfloat16* __restrict__ Xb,
    float* __restrict__ nrm, unsigned* __restrict__ ap,
    unsigned* __restrict__ an, int K) {
    const int row = blockIdx.x;
    const int tid = threadIdx.x;
    const float* xr = X + (size_t)row * K;
    __hip_bfloat16* xbr = Xb + (size_t)row * K;
    float s = 0.0f;
    for (int c = tid * 4; c < K; c += 256 * 4) {
        float4 v = *(const float4*)(xr + c);
        union { __hip_bfloat16 h[4]; uint2 u; } p;
        p.h[0] = __float2bfloat16(v.x);
        p.h[1] = __float2bfloat16(v.y);
        p.h[2] = __float2bfloat16(v.z);
        p.h[3] = __float2bfloat16(v.w);
        *(uint2*)(xbr + c) = p.u;
        float f0 = __bfloat162float(p.h[0]);
        float f1 = __bfloat162float(p.h[1]);
        float f2 = __bfloat162float(p.h[2]);
        float f3 = __bfloat162float(p.h[3]);
        s += f0 * f0 + f1 * f1 + f2 * f2 + f3 * f3;
    }
    for (int off = 32; off > 0; off >>= 1) s += __shfl_down(s, off, 64);
    __shared__ float wsum[4];
    const int wave = tid >> 6, lane = tid & 63;
    if (lane == 0) wsum[wave] = s;
    __syncthreads();
    if (tid == 0) {
        nrm[row] = wsum[0] + wsum[1] + wsum[2] + wsum[3];
        ap[row] = 0u;           // dist_ap >= 0 always (self is a positive)
        an[row] = 0x7F800000u;  // +inf
    }
}

// 128x128 tile of G = Xb * Xb^T, BK=32, 4 waves (2x2), 4x4 16x16x32 MFMA
// subtiles per wave. Epilogue: distance + label mask + per-row max/min,
// combined into global ap/an via monotone uint atomics.
__global__ __launch_bounds__(256) void gemm_reduce_kernel(
    const __hip_bfloat16* __restrict__ Xb, const float* __restrict__ nrm,
    const int* __restrict__ Y, unsigned* __restrict__ ap,
    unsigned* __restrict__ an, int N, int K) {
    __shared__ __align__(16) __hip_bfloat16 sA[128 * 32];
    __shared__ __align__(16) __hip_bfloat16 sB[128 * 32];
    __shared__ int sYr[128], sYc[128];
    __shared__ float sNr[128], sNc[128];
    __shared__ float redmax[2][2][64];
    __shared__ float redmin[2][2][64];

    const int tid = threadIdx.x;
    const int wave = tid >> 6;
    const int lane = tid & 63;
    const int q = lane >> 4;   // quad within wave
    const int lc = lane & 15;  // col within 16x16 subtile
    const int wr = wave >> 1;  // wave row (0..1)
    const int wc = wave & 1;   // wave col (0..1)
    const int rowBase = blockIdx.y * 128;
    const int colBase = blockIdx.x * 128;

    if (tid < 128) {
        sYr[tid] = Y[rowBase + tid];
        sNr[tid] = nrm[rowBase + tid];
    } else {
        int t = tid - 128;
        sYc[t] = Y[colBase + t];
        sNc[t] = nrm[colBase + t];
    }

    f32x4 acc[4][4];
#pragma unroll
    for (int i = 0; i < 4; i++)
#pragma unroll
        for (int j = 0; j < 4; j++) acc[i][j] = (f32x4){0.f, 0.f, 0.f, 0.f};

    // Staging: per wave, 32 rows of each tile; each global_load_lds covers
    // 16 rows (64 lanes x 16B = 1KB). LDS layout [128 rows][32 bf16] matches
    // the wave-uniform-base + lane*16 write pattern exactly (no padding).
    const char* gA = (const char*)(Xb + (size_t)(rowBase + wave * 32 + (lane >> 2)) * K + (lane & 3) * 8);
    const char* gB = (const char*)(Xb + (size_t)(colBase + wave * 32 + (lane >> 2)) * K + (lane & 3) * 8);
    char* lA = (char*)sA + wave * 2048;
    char* lB = (char*)sB + wave * 2048;
    const size_t g16 = (size_t)16 * K * 2;  // 16 rows, bytes

    for (int kt = 0; kt < K; kt += 32) {
        const size_t go = (size_t)kt * 2;
        gl2lds16(gA + go, lA);
        gl2lds16(gA + go + g16, lA + 1024);
        gl2lds16(gB + go, lB);
        gl2lds16(gB + go + g16, lB + 1024);
        __syncthreads();

        bf16x8 af[4], bfr[4];
#pragma unroll
        for (int b = 0; b < 4; b++) {
            af[b]  = *(const bf16x8*)((const char*)sA + ((size_t)((wr * 64 + b * 16 + lc) * 32 + q * 8) * 2));
            bfr[b] = *(const bf16x8*)((const char*)sB + ((size_t)((wc * 64 + b * 16 + lc) * 32 + q * 8) * 2));
        }
#pragma unroll
        for (int bi = 0; bi < 4; bi++)
#pragma unroll
            for (int bj = 0; bj < 4; bj++)
                acc[bi][bj] = __builtin_amdgcn_mfma_f32_16x16x32_bf16(
                    af[bi], bfr[bj], acc[bi][bj], 0, 0, 0);
        __syncthreads();
    }

    // Epilogue: distance + mask + per-row reduce over this block's 128 cols.
    // C/D layout: col = lane&15, row = (lane>>4)*4 + reg.
    float rmx[4][4], rmn[4][4];
#pragma unroll
    for (int bi = 0; bi < 4; bi++)
#pragma unroll
        for (int r = 0; r < 4; r++) { rmx[bi][r] = -1.0f; rmn[bi][r] = 3.0e38f; }

#pragma unroll
    for (int bj = 0; bj < 4; bj++) {
        const int ct = wc * 64 + bj * 16 + lc;
        const int yc = sYc[ct];
        const float nc = sNc[ct];
#pragma unroll
        for (int bi = 0; bi < 4; bi++) {
            const int rbase = wr * 64 + bi * 16 + q * 4;
#pragma unroll
            for (int r = 0; r < 4; r++) {
                const int rt = rbase + r;
                float d2 = sNr[rt] + nc - 2.0f * acc[bi][bj][r];
                float d = sqrtf(fmaxf(d2, 0.0f));
                bool same = (sYr[rt] == yc);
                rmx[bi][r] = fmaxf(rmx[bi][r], same ? d : -1.0f);
                rmn[bi][r] = fminf(rmn[bi][r], same ? 3.0e38f : d);
            }
        }
    }

    // Butterfly across the 16 lanes of a quad (same row, 16 cols).
#pragma unroll
    for (int bi = 0; bi < 4; bi++)
#pragma unroll
        for (int r = 0; r < 4; r++) {
            float mx = rmx[bi][r], mn = rmn[bi][r];
            for (int off = 1; off < 16; off <<= 1) {
                mx = fmaxf(mx, __shfl_xor(mx, off, 64));
                mn = fminf(mn, __shfl_xor(mn, off, 64));
            }
            if (lc == 0) {
                redmax[wr][wc][bi * 16 + q * 4 + r] = mx;
                redmin[wr][wc][bi * 16 + q * 4 + r] = mn;
            }
        }
    __syncthreads();

    if (tid < 128) {
        const int w2 = tid >> 6, r64 = tid & 63;
        float mx = fmaxf(redmax[w2][0][r64], redmax[w2][1][r64]);
        float mn = fminf(redmin[w2][0][r64], redmin[w2][1][r64]);
        // Non-negative floats: uint compare == float compare. Clamp mx to 0
        // (true dist_ap >= 0; avoids the -1 "no positive in tile" sentinel).
        atomicMax(&ap[rowBase + tid], __float_as_uint(fmaxf(mx, 0.0f)));
        atomicMin(&an[rowBase + tid], __float_as_uint(mn));
    }
}

__global__ __launch_bounds__(256) void finalize_kernel(
    const unsigned* __restrict__ ap, const unsigned* __restrict__ an,
    float* __restrict__ out, int N) {
    const int tid = threadIdx.x;
    float s = 0.0f;
    for (int i = tid; i < N; i += 256) {
        float a = __uint_as_float(ap[i]);
        float b = __uint_as_float(an[i]);
        s += fmaxf(a - b + MARGIN, 0.0f);
    }
    for (int off = 32; off > 0; off >>= 1) s += __shfl_down(s, off, 64);
    __shared__ float wsum[4];
    const int wave = tid >> 6, lane = tid & 63;
    if (lane == 0) wsum[wave] = s;
    __syncthreads();
    if (tid == 0) out[0] = (wsum[0] + wsum[1] + wsum[2] + wsum[3]) / (float)N;
}

extern "C" void kernel_launch(void* const* d_in, const int* in_sizes, int n_in,
                              void* d_out, int out_size, void* d_ws, size_t ws_size,
                              hipStream_t stream) {
    const float* X = (const float*)d_in[0];
    const int* Y = (const int*)d_in[1];
    float* out = (float*)d_out;
    const int N = in_sizes[1];          // 4096
    const int K = in_sizes[0] / N;      // 2048

    char* ws = (char*)d_ws;
    __hip_bfloat16* Xb = (__hip_bfloat16*)ws;                       // N*K*2 bytes
    float* nrm = (float*)(ws + (size_t)N * K * sizeof(__hip_bfloat16));
    unsigned* ap = (unsigned*)((char*)nrm + (size_t)N * 4);
    unsigned* an = (unsigned*)((char*)ap + (size_t)N * 4);

    convert_norm_kernel<<<N, 256, 0, stream>>>(X, Xb, nrm, ap, an, K);
    dim3 grid(N / 128, N / 128);
    gemm_reduce_kernel<<<grid, 256, 0, stream>>>(Xb, nrm, Y, ap, an, N, K);
    finalize_kernel<<<1, 256, 0, stream>>>(ap, an, out, N);
}

// Round 2
// 166.400 us; speedup vs baseline: 1.1494x; 1.1494x over previous
//
#include <hip/hip_runtime.h>
#include <hip/hip_bf16.h>

typedef __attribute__((ext_vector_type(8))) short bf16x8;
typedef __attribute__((ext_vector_type(4))) float f32x4;

#define MARGIN 0.3f
#define BIGF 3.0e38f

__device__ __forceinline__ void gl2lds16(const void* g, void* l) {
    __builtin_amdgcn_global_load_lds(
        (const __attribute__((address_space(1))) void*)g,
        (__attribute__((address_space(3))) void*)l,
        16, 0, 0);
}

// One block per row: fp32 -> bf16 cast, fp32 row norm (of the bf16-rounded
// values, for consistency with the MFMA dot products), and init ap/an.
__global__ __launch_bounds__(256) void convert_norm_kernel(
    const float* __restrict__ X, __hip_bfloat16* __restrict__ Xb,
    float* __restrict__ nrm, unsigned* __restrict__ ap,
    unsigned* __restrict__ an, int K) {
    const int row = blockIdx.x;
    const int tid = threadIdx.x;
    const float* xr = X + (size_t)row * K;
    __hip_bfloat16* xbr = Xb + (size_t)row * K;
    float s = 0.0f;
    for (int c = tid * 4; c < K; c += 256 * 4) {
        float4 v = *(const float4*)(xr + c);
        union { __hip_bfloat16 h[4]; uint2 u; } p;
        p.h[0] = __float2bfloat16(v.x);
        p.h[1] = __float2bfloat16(v.y);
        p.h[2] = __float2bfloat16(v.z);
        p.h[3] = __float2bfloat16(v.w);
        *(uint2*)(xbr + c) = p.u;
        float f0 = __bfloat162float(p.h[0]);
        float f1 = __bfloat162float(p.h[1]);
        float f2 = __bfloat162float(p.h[2]);
        float f3 = __bfloat162float(p.h[3]);
        s += f0 * f0 + f1 * f1 + f2 * f2 + f3 * f3;
    }
    for (int off = 32; off > 0; off >>= 1) s += __shfl_down(s, off, 64);
    __shared__ float wsum[4];
    const int wave = tid >> 6, lane = tid & 63;
    if (lane == 0) wsum[wave] = s;
    __syncthreads();
    if (tid == 0) {
        nrm[row] = wsum[0] + wsum[1] + wsum[2] + wsum[3];
        ap[row] = 0u;           // dist_ap >= 0 always (self is a positive)
        an[row] = 0x7F800000u;  // +inf
    }
}

// Upper-triangle 128x128 tiles of G = Xb * Xb^T (528 blocks for N=4096).
// BK=64, XOR-swizzled LDS (physical 16B chunk = logical ^ (row&7)) so
// fragment ds_read_b128 is 2-way per quad (free) instead of 8-way.
// Epilogue reduces BOTH directions (rows -> ap/an[rowBase+..],
// cols -> ap/an[colBase+..]); diagonal tiles double-update idempotently.
__global__ __launch_bounds__(256) void gemm_reduce_kernel(
    const __hip_bfloat16* __restrict__ Xb, const float* __restrict__ nrm,
    const int* __restrict__ Y, unsigned* __restrict__ ap,
    unsigned* __restrict__ an, int N, int K) {
    __shared__ __align__(16) __hip_bfloat16 sA[128 * 64];  // [row][128B], swizzled
    __shared__ __align__(16) __hip_bfloat16 sB[128 * 64];
    __shared__ int sYr[128], sYc[128];
    __shared__ float sNr[128], sNc[128];
    __shared__ float redmax[2][2][64], redmin[2][2][64];    // row-side
    __shared__ float credmax[2][2][64], credmin[2][2][64];  // col-side

    const int tid = threadIdx.x;
    const int wave = tid >> 6;
    const int lane = tid & 63;
    const int q = lane >> 4;   // quad within wave
    const int lc = lane & 15;  // col within 16x16 subtile
    const int wr = wave >> 1;  // wave row (0..1)
    const int wc = wave & 1;   // wave col (0..1)

    // Decode upper-triangle tile index (bi <= bj), NB = N/128.
    const int NB = N >> 7;
    int bi = 0, rem = blockIdx.x;
    while (rem >= NB - bi) { rem -= NB - bi; bi++; }
    const int bj = bi + rem;
    const int rowBase = bi * 128;
    const int colBase = bj * 128;

    if (tid < 128) {
        sYr[tid] = Y[rowBase + tid];
        sNr[tid] = nrm[rowBase + tid];
    } else {
        int t = tid - 128;
        sYc[t] = Y[colBase + t];
        sNc[t] = nrm[colBase + t];
    }

    f32x4 acc[4][4];
#pragma unroll
    for (int i = 0; i < 4; i++)
#pragma unroll
        for (int j = 0; j < 4; j++) acc[i][j] = (f32x4){0.f, 0.f, 0.f, 0.f};

    // Staging: per wave, 32 rows x 128B of each tile; each gl2lds covers
    // 8 rows (64 lanes x 16B). Lane l -> LDS row l>>3, physical chunk l&7;
    // the lane fetches LOGICAL chunk (l&7)^(l>>3) so reads can unswizzle.
    const int rsub = lane >> 3;              // row within 8-row group
    const int jchunk = (lane & 7) ^ rsub;    // logical 16B chunk to fetch
    const char* gA = (const char*)(Xb + (size_t)(rowBase + wave * 32 + rsub) * K) + jchunk * 16;
    const char* gB = (const char*)(Xb + (size_t)(colBase + wave * 32 + rsub) * K) + jchunk * 16;
    char* lA = (char*)sA + wave * 4096;  // 32 rows * 128 B
    char* lB = (char*)sB + wave * 4096;
    const size_t g8 = (size_t)8 * K * 2;  // 8 rows, bytes

    // Per-lane fragment read offsets within a row (swizzle depends on lc&7).
    const int xo0 = ((q ^ (lc & 7)) * 16);        // kk=0: logical chunk q
    const int xo1 = (((4 + q) ^ (lc & 7)) * 16);  // kk=1: logical chunk 4+q
    const int arow = (wr * 64 + lc) * 128;        // byte base of A frag rows
    const int brow = (wc * 64 + lc) * 128;

    for (int kt = 0; kt < K; kt += 64) {
        const size_t go = (size_t)kt * 2;
#pragma unroll
        for (int i = 0; i < 4; i++) {
            gl2lds16(gA + go + i * g8, lA + i * 1024);
            gl2lds16(gB + go + i * g8, lB + i * 1024);
        }
        __syncthreads();  // drains vmcnt for gl2lds

#pragma unroll
        for (int kk = 0; kk < 2; kk++) {
            const int xo = kk ? xo1 : xo0;
            bf16x8 af[4], bfr[4];
#pragma unroll
            for (int b = 0; b < 4; b++) {
                af[b]  = *(const bf16x8*)((const char*)sA + arow + b * 2048 + xo);
                bfr[b] = *(const bf16x8*)((const char*)sB + brow + b * 2048 + xo);
            }
#pragma unroll
            for (int i = 0; i < 4; i++)
#pragma unroll
                for (int j = 0; j < 4; j++)
                    acc[i][j] = __builtin_amdgcn_mfma_f32_16x16x32_bf16(
                        af[i], bfr[j], acc[i][j], 0, 0, 0);
        }
        __syncthreads();
    }

    // Epilogue. C/D layout: col = lane&15 (within subtile), row = q*4 + reg.
    float rmx[4][4], rmn[4][4];  // per (bi-subtile, reg): row-side
    float cmx[4], cmn[4];        // per bj-subtile: col-side
#pragma unroll
    for (int i = 0; i < 4; i++) {
        cmx[i] = -1.0f; cmn[i] = BIGF;
#pragma unroll
        for (int r = 0; r < 4; r++) { rmx[i][r] = -1.0f; rmn[i][r] = BIGF; }
    }

#pragma unroll
    for (int sj = 0; sj < 4; sj++) {
        const int ct = wc * 64 + sj * 16 + lc;
        const int yc = sYc[ct];
        const float nc = sNc[ct];
#pragma unroll
        for (int si = 0; si < 4; si++) {
            const int rbase = wr * 64 + si * 16 + q * 4;
#pragma unroll
            for (int r = 0; r < 4; r++) {
                const int rt = rbase + r;
                float d2 = sNr[rt] + nc - 2.0f * acc[si][sj][r];
                float d = sqrtf(fmaxf(d2, 0.0f));
                bool same = (sYr[rt] == yc);
                float dp = same ? d : -1.0f;
                float dn = same ? BIGF : d;
                rmx[si][r] = fmaxf(rmx[si][r], dp);
                rmn[si][r] = fminf(rmn[si][r], dn);
                cmx[sj] = fmaxf(cmx[sj], dp);
                cmn[sj] = fminf(cmn[sj], dn);
            }
        }
    }

    // Row-side: butterfly across the 16 lanes of a quad (16 cols, same row).
#pragma unroll
    for (int si = 0; si < 4; si++)
#pragma unroll
        for (int r = 0; r < 4; r++) {
            float mx = rmx[si][r], mn = rmn[si][r];
            for (int off = 1; off < 16; off <<= 1) {
                mx = fmaxf(mx, __shfl_xor(mx, off, 64));
                mn = fminf(mn, __shfl_xor(mn, off, 64));
            }
            if (lc == 0) {
                redmax[wr][wc][si * 16 + q * 4 + r] = mx;
                redmin[wr][wc][si * 16 + q * 4 + r] = mn;
            }
        }

    // Col-side: per lane cmx[sj] already reduced over (si, r); reduce across
    // quads (q differs -> different rows, same col) via xor 16 and 32.
#pragma unroll
    for (int sj = 0; sj < 4; sj++) {
        float mx = cmx[sj], mn = cmn[sj];
        mx = fmaxf(mx, __shfl_xor(mx, 16, 64));
        mn = fminf(mn, __shfl_xor(mn, 16, 64));
        mx = fmaxf(mx, __shfl_xor(mx, 32, 64));
        mn = fminf(mn, __shfl_xor(mn, 32, 64));
        if (q == 0) {
            credmax[wr][wc][sj * 16 + lc] = mx;
            credmin[wr][wc][sj * 16 + lc] = mn;
        }
    }
    __syncthreads();

    if (tid < 128) {
        const int w2 = tid >> 6, r64 = tid & 63;
        // Row side: combine wave-cols. Non-negative floats: uint cmp == float
        // cmp; clamp max to 0 (true dist_ap >= 0 via diagonal self-pair).
        float mx = fmaxf(redmax[w2][0][r64], redmax[w2][1][r64]);
        float mn = fminf(redmin[w2][0][r64], redmin[w2][1][r64]);
        atomicMax(&ap[rowBase + tid], __float_as_uint(fmaxf(mx, 0.0f)));
        atomicMin(&an[rowBase + tid], __float_as_uint(mn));
        // Col side: combine wave-rows.
        float cx = fmaxf(credmax[0][w2][r64], credmax[1][w2][r64]);
        float cn = fminf(credmin[0][w2][r64], credmin[1][w2][r64]);
        atomicMax(&ap[colBase + tid], __float_as_uint(fmaxf(cx, 0.0f)));
        atomicMin(&an[colBase + tid], __float_as_uint(cn));
    }
}

__global__ __launch_bounds__(256) void finalize_kernel(
    const unsigned* __restrict__ ap, const unsigned* __restrict__ an,
    float* __restrict__ out, int N) {
    const int tid = threadIdx.x;
    float s = 0.0f;
    for (int i = tid; i < N; i += 256) {
        float a = __uint_as_float(ap[i]);
        float b = __uint_as_float(an[i]);
        s += fmaxf(a - b + MARGIN, 0.0f);
    }
    for (int off = 32; off > 0; off >>= 1) s += __shfl_down(s, off, 64);
    __shared__ float wsum[4];
    const int wave = tid >> 6, lane = tid & 63;
    if (lane == 0) wsum[wave] = s;
    __syncthreads();
    if (tid == 0) out[0] = (wsum[0] + wsum[1] + wsum[2] + wsum[3]) / (float)N;
}

extern "C" void kernel_launch(void* const* d_in, const int* in_sizes, int n_in,
                              void* d_out, int out_size, void* d_ws, size_t ws_size,
                              hipStream_t stream) {
    const float* X = (const float*)d_in[0];
    const int* Y = (const int*)d_in[1];
    float* out = (float*)d_out;
    const int N = in_sizes[1];          // 4096
    const int K = in_sizes[0] / N;      // 2048

    char* ws = (char*)d_ws;
    __hip_bfloat16* Xb = (__hip_bfloat16*)ws;                       // N*K*2 bytes
    float* nrm = (float*)(ws + (size_t)N * K * sizeof(__hip_bfloat16));
    unsigned* ap = (unsigned*)((char*)nrm + (size_t)N * 4);
    unsigned* an = (unsigned*)((char*)ap + (size_t)N * 4);

    convert_norm_kernel<<<N, 256, 0, stream>>>(X, Xb, nrm, ap, an, K);
    const int NB = N / 128;
    const int nblocks = NB * (NB + 1) / 2;  // upper-triangle tiles
    gemm_reduce_kernel<<<nblocks, 256, 0, stream>>>(Xb, nrm, Y, ap, an, N, K);
    finalize_kernel<<<1, 256, 0, stream>>>(ap, an, out, N);
}

// Round 3
// 162.396 us; speedup vs baseline: 1.1777x; 1.0247x over previous
//
#include <hip/hip_runtime.h>
#include <hip/hip_bf16.h>

typedef __attribute__((ext_vector_type(8))) short bf16x8;
typedef __attribute__((ext_vector_type(4))) float f32x4;

#define MARGIN 0.3f
#define BIGF 3.0e38f

__device__ __forceinline__ void gl2lds16(const void* g, void* l) {
    __builtin_amdgcn_global_load_lds(
        (const __attribute__((address_space(1))) void*)g,
        (__attribute__((address_space(3))) void*)l,
        16, 0, 0);
}

// One block per row: fp32 -> bf16 cast, fp32 row norm (of the bf16-rounded
// values, for consistency with MFMA dots), init ap/an, zero done-counter.
__global__ __launch_bounds__(256) void convert_norm_kernel(
    const float* __restrict__ X, __hip_bfloat16* __restrict__ Xb,
    float* __restrict__ nrm, unsigned* __restrict__ ap,
    unsigned* __restrict__ an, unsigned* __restrict__ cnt, int K) {
    const int row = blockIdx.x;
    const int tid = threadIdx.x;
    const float* xr = X + (size_t)row * K;
    __hip_bfloat16* xbr = Xb + (size_t)row * K;
    float s = 0.0f;
    for (int c = tid * 4; c < K; c += 256 * 4) {
        float4 v = *(const float4*)(xr + c);
        union { __hip_bfloat16 h[4]; uint2 u; } p;
        p.h[0] = __float2bfloat16(v.x);
        p.h[1] = __float2bfloat16(v.y);
        p.h[2] = __float2bfloat16(v.z);
        p.h[3] = __float2bfloat16(v.w);
        *(uint2*)(xbr + c) = p.u;
        float f0 = __bfloat162float(p.h[0]);
        float f1 = __bfloat162float(p.h[1]);
        float f2 = __bfloat162float(p.h[2]);
        float f3 = __bfloat162float(p.h[3]);
        s += f0 * f0 + f1 * f1 + f2 * f2 + f3 * f3;
    }
    for (int off = 32; off > 0; off >>= 1) s += __shfl_down(s, off, 64);
    __shared__ float wsum[4];
    const int wave = tid >> 6, lane = tid & 63;
    if (lane == 0) wsum[wave] = s;
    __syncthreads();
    if (tid == 0) {
        nrm[row] = wsum[0] + wsum[1] + wsum[2] + wsum[3];
        ap[row] = 0u;           // dist_ap >= 0 always (self is a positive)
        an[row] = 0x7F800000u;  // +inf
        if (row == 0) *cnt = 0u;
    }
}

// Upper-triangle coverage with 64x128 tiles: for col-block j (128 wide),
// row-blocks r = 0..2j+1 (64 wide) -> 1056 blocks at N=4096 (4.1/CU for
// TLP; R2's 528 128x128 blocks were latency-bound at 2.06/CU).
// BK=64, XOR-swizzled LDS (physical 16B chunk = logical ^ (row&7), 0
// conflicts measured in R2 with identical lane math). 4 waves, each owns
// 64 rows x 32 cols (4x2 subtiles of 16x16x32 bf16 MFMA).
// Epilogue reduces rows (cross-wave via LDS) and cols (wave-local), updates
// global ap/an via monotone uint atomics; LAST block computes the loss.
__global__ __launch_bounds__(256) void gemm_reduce_kernel(
    const __hip_bfloat16* __restrict__ Xb, const float* __restrict__ nrm,
    const int* __restrict__ Y, unsigned* __restrict__ ap,
    unsigned* __restrict__ an, unsigned* __restrict__ cnt,
    float* __restrict__ out, int N, int K) {
    __shared__ __align__(16) __hip_bfloat16 sA[64 * 64];   // 8KB  [64 rows][128B]
    __shared__ __align__(16) __hip_bfloat16 sB[128 * 64];  // 16KB [128 rows][128B]
    __shared__ int sYr[64], sYc[128];
    __shared__ float sNr[64], sNc[128];
    __shared__ float redmax[4][64], redmin[4][64];  // row-side, per wave
    __shared__ float credmax[128], credmin[128];    // col-side
    __shared__ unsigned s_done;

    const int tid = threadIdx.x;
    const int wave = tid >> 6;
    const int lane = tid & 63;
    const int q = lane >> 4;   // quad within wave
    const int lc = lane & 15;  // col within 16x16 subtile

    // Decode (col-block j, row-block r): blocks for col j are j(j+1)..(j+1)(j+2).
    int j = 0;
    {
        const int b = blockIdx.x;
        while ((j + 1) * (j + 2) <= b) j++;
    }
    const int r = blockIdx.x - j * (j + 1);  // 0..2j+1
    const int rowBase = r * 64;
    const int colBase = j * 128;

    if (tid < 64) {
        sYr[tid] = Y[rowBase + tid];
        sNr[tid] = nrm[rowBase + tid];
    } else if (tid < 192) {
        int t = tid - 64;
        sYc[t] = Y[colBase + t];
        sNc[t] = nrm[colBase + t];
    }

    f32x4 acc[4][2];
#pragma unroll
    for (int i = 0; i < 4; i++)
#pragma unroll
        for (int jj = 0; jj < 2; jj++) acc[i][jj] = (f32x4){0.f, 0.f, 0.f, 0.f};

    // Staging: lane l -> LDS row l>>3 (of an 8-row group), physical chunk
    // l&7; lane fetches LOGICAL chunk (l&7)^(l>>3). Per iter per wave:
    // A rows wave*16+{0,8}, B rows wave*32+{0,8,16,24}.
    const int rsub = lane >> 3;
    const int jchunk = (lane & 7) ^ rsub;
    const char* gA = (const char*)(Xb + (size_t)(rowBase + wave * 16 + rsub) * K) + jchunk * 16;
    const char* gB = (const char*)(Xb + (size_t)(colBase + wave * 32 + rsub) * K) + jchunk * 16;
    char* lA = (char*)sA + wave * 2048;  // 16 rows * 128B
    char* lB = (char*)sB + wave * 4096;  // 32 rows * 128B
    const size_t g8 = (size_t)8 * K * 2;

    // Fragment read offsets: row m = subtile*16 + lc; kk=0 logical chunk q,
    // kk=1 logical chunk 4+q; physical = logical ^ (lc&7).
    const int xo0 = ((q ^ (lc & 7)) * 16);
    const int xo1 = (((4 + q) ^ (lc & 7)) * 16);
    const int arow = lc * 128;               // + si*2048
    const int brow = (wave * 32 + lc) * 128; // + sj*2048

    for (int kt = 0; kt < K; kt += 64) {
        const size_t go = (size_t)kt * 2;
        gl2lds16(gA + go, lA);
        gl2lds16(gA + go + g8, lA + 1024);
        gl2lds16(gB + go, lB);
        gl2lds16(gB + go + g8, lB + 1024);
        gl2lds16(gB + go + 2 * g8, lB + 2048);
        gl2lds16(gB + go + 3 * g8, lB + 3072);
        __syncthreads();

#pragma unroll
        for (int kk = 0; kk < 2; kk++) {
            const int xo = kk ? xo1 : xo0;
            bf16x8 af[4], bfr[2];
#pragma unroll
            for (int b = 0; b < 4; b++)
                af[b] = *(const bf16x8*)((const char*)sA + arow + b * 2048 + xo);
#pragma unroll
            for (int b = 0; b < 2; b++)
                bfr[b] = *(const bf16x8*)((const char*)sB + brow + b * 2048 + xo);
#pragma unroll
            for (int si = 0; si < 4; si++)
#pragma unroll
                for (int sj = 0; sj < 2; sj++)
                    acc[si][sj] = __builtin_amdgcn_mfma_f32_16x16x32_bf16(
                        af[si], bfr[sj], acc[si][sj], 0, 0, 0);
        }
        __syncthreads();
    }

    // Epilogue. C/D layout: col = lc, row = q*4 + reg (within subtile).
    float rmx[4][4], rmn[4][4];
    float cmx[2], cmn[2];
#pragma unroll
    for (int i = 0; i < 4; i++)
#pragma unroll
        for (int rr = 0; rr < 4; rr++) { rmx[i][rr] = -1.0f; rmn[i][rr] = BIGF; }
    cmx[0] = cmx[1] = -1.0f; cmn[0] = cmn[1] = BIGF;

#pragma unroll
    for (int sj = 0; sj < 2; sj++) {
        const int ct = wave * 32 + sj * 16 + lc;
        const int yc = sYc[ct];
        const float nc = sNc[ct];
#pragma unroll
        for (int si = 0; si < 4; si++) {
            const int rbase = si * 16 + q * 4;
#pragma unroll
            for (int rr = 0; rr < 4; rr++) {
                const int rt = rbase + rr;
                float d2 = sNr[rt] + nc - 2.0f * acc[si][sj][rr];
                float d = sqrtf(fmaxf(d2, 0.0f));
                bool same = (sYr[rt] == yc);
                float dp = same ? d : -1.0f;
                float dn = same ? BIGF : d;
                rmx[si][rr] = fmaxf(rmx[si][rr], dp);
                rmn[si][rr] = fminf(rmn[si][rr], dn);
                cmx[sj] = fmaxf(cmx[sj], dp);
                cmn[sj] = fminf(cmn[sj], dn);
            }
        }
    }

    // Row-side: butterfly across the 16 lanes of a quad (same row, 16 cols).
#pragma unroll
    for (int si = 0; si < 4; si++)
#pragma unroll
        for (int rr = 0; rr < 4; rr++) {
            float mx = rmx[si][rr], mn = rmn[si][rr];
            for (int off = 1; off < 16; off <<= 1) {
                mx = fmaxf(mx, __shfl_xor(mx, off, 64));
                mn = fminf(mn, __shfl_xor(mn, off, 64));
            }
            if (lc == 0) {
                redmax[wave][si * 16 + q * 4 + rr] = mx;
                redmin[wave][si * 16 + q * 4 + rr] = mn;
            }
        }

    // Col-side: reduce across quads (different rows, same col).
#pragma unroll
    for (int sj = 0; sj < 2; sj++) {
        float mx = cmx[sj], mn = cmn[sj];
        mx = fmaxf(mx, __shfl_xor(mx, 16, 64));
        mn = fminf(mn, __shfl_xor(mn, 16, 64));
        mx = fmaxf(mx, __shfl_xor(mx, 32, 64));
        mn = fminf(mn, __shfl_xor(mn, 32, 64));
        if (q == 0) {
            credmax[wave * 32 + sj * 16 + lc] = mx;
            credmin[wave * 32 + sj * 16 + lc] = mn;
        }
    }
    __syncthreads();

    // Non-negative floats: uint cmp == float cmp. Clamp max to 0 (true
    // dist_ap >= 0 via the diagonal self-pair).
    if (tid < 64) {
        float mx = fmaxf(fmaxf(redmax[0][tid], redmax[1][tid]),
                         fmaxf(redmax[2][tid], redmax[3][tid]));
        float mn = fminf(fminf(redmin[0][tid], redmin[1][tid]),
                         fminf(redmin[2][tid], redmin[3][tid]));
        atomicMax(&ap[rowBase + tid], __float_as_uint(fmaxf(mx, 0.0f)));
        atomicMin(&an[rowBase + tid], __float_as_uint(mn));
    } else if (tid < 192) {
        int c = tid - 64;
        atomicMax(&ap[colBase + c], __float_as_uint(fmaxf(credmax[c], 0.0f)));
        atomicMin(&an[colBase + c], __float_as_uint(credmin[c]));
    }

    // Last block computes the loss (release: threadfence before counter
    // increment; acquire: threadfence after observing last + agent-scope
    // atomic loads of ap/an).
    __syncthreads();
    if (tid == 0) {
        __threadfence();
        s_done = atomicAdd(cnt, 1u);
    }
    __syncthreads();
    if (s_done == gridDim.x - 1) {
        __threadfence();
        float s = 0.0f;
        for (int i = tid; i < N; i += 256) {
            unsigned ua = __hip_atomic_load(&ap[i], __ATOMIC_RELAXED,
                                            __HIP_MEMORY_SCOPE_AGENT);
            unsigned ub = __hip_atomic_load(&an[i], __ATOMIC_RELAXED,
                                            __HIP_MEMORY_SCOPE_AGENT);
            s += fmaxf(__uint_as_float(ua) - __uint_as_float(ub) + MARGIN, 0.0f);
        }
        for (int off = 32; off > 0; off >>= 1) s += __shfl_down(s, off, 64);
        // reuse credmax as scratch
        if ((tid & 63) == 0) credmax[tid >> 6] = s;
        __syncthreads();
        if (tid == 0)
            out[0] = (credmax[0] + credmax[1] + credmax[2] + credmax[3]) / (float)N;
    }
}

extern "C" void kernel_launch(void* const* d_in, const int* in_sizes, int n_in,
                              void* d_out, int out_size, void* d_ws, size_t ws_size,
                              hipStream_t stream) {
    const float* X = (const float*)d_in[0];
    const int* Y = (const int*)d_in[1];
    float* out = (float*)d_out;
    const int N = in_sizes[1];          // 4096
    const int K = in_sizes[0] / N;      // 2048

    char* ws = (char*)d_ws;
    __hip_bfloat16* Xb = (__hip_bfloat16*)ws;                       // N*K*2 bytes
    float* nrm = (float*)(ws + (size_t)N * K * sizeof(__hip_bfloat16));
    unsigned* ap = (unsigned*)((char*)nrm + (size_t)N * 4);
    unsigned* an = (unsigned*)((char*)ap + (size_t)N * 4);
    unsigned* cnt = (unsigned*)((char*)an + (size_t)N * 4);

    convert_norm_kernel<<<N, 256, 0, stream>>>(X, Xb, nrm, ap, an, cnt, K);
    const int NB = N / 128;
    const int nblocks = NB * (NB + 1);  // 64x128 tiles covering the triangle
    gemm_reduce_kernel<<<nblocks, 256, 0, stream>>>(Xb, nrm, Y, ap, an, cnt,
                                                    out, N, K);
}